// Round 2
// baseline (357.894 us; speedup 1.0000x reference)
//
#include <hip/hip_runtime.h>
#include <hip/hip_bf16.h>
#include <cstdint>

// Transducer joint network:
//   enc (4,160,640) fp32, dec (4,80,640) fp32, W1 (1280,640), b1 (640),
//   W2 (640,1024), b2 (1024).  out = (4,160,80,1024) fp32 = 52.4M floats.
#define D_    640      // De = Dd = inner
#define V_    1024
#define M_    51200    // B*T*U

typedef __bf16 bf16x8 __attribute__((ext_vector_type(8)));
typedef float floatx4 __attribute__((ext_vector_type(4)));

__device__ __forceinline__ void g2l16(const void* g, void* l) {
    __builtin_amdgcn_global_load_lds((const __attribute__((address_space(1))) void*)g,
                                     (__attribute__((address_space(3))) void*)l,
                                     16, 0, 0);
}

__device__ __forceinline__ float fast_tanh(float x) {
    float e = __builtin_amdgcn_exp2f(x * 2.8853900817779268f); // 2*log2(e)
    return 1.0f - 2.0f * __builtin_amdgcn_rcpf(e + 1.0f);
}

// ---------------------------------------------------------------------------
// Kernel 1: all dtype conversions + transposes in one launch.
//  [0,200)     enc fp32 -> enc_b bf16 (row-major, 640x640)
//  [200,320)   dec fp32 -> dec_b bf16 (rows 0..319; rows 320..383 zeroed pad)
//  [320,720)   W1[:640]  -> W1t_enc bf16 (N x K = 640x640)
//  [720,1120)  W1[640:]  -> W1t_dec bf16 (640x640)
//  [1120,1760) W2        -> W2t bf16 (1024x640)
// ---------------------------------------------------------------------------
__global__ __launch_bounds__(256) void convert_kernel(
    const float* __restrict__ enc, const float* __restrict__ dec,
    const float* __restrict__ W1, const float* __restrict__ W2,
    __bf16* __restrict__ enc_b, __bf16* __restrict__ dec_b,
    __bf16* __restrict__ W1t_enc, __bf16* __restrict__ W1t_dec,
    __bf16* __restrict__ W2t) {
    __shared__ __bf16 tile[32][33];
    const int bid = blockIdx.x;
    const int tid = threadIdx.x;

    if (bid < 320) {  // straight casts (8 elems/thread, 16B loads, 16B stores)
        bf16x8 o;
        if (bid < 200) {
            const size_t g = (size_t)bid * 2048 + (size_t)tid * 8;
            floatx4 a = *(const floatx4*)(enc + g);
            floatx4 b = *(const floatx4*)(enc + g + 4);
#pragma unroll
            for (int i = 0; i < 4; i++) { o[i] = (__bf16)a[i]; o[i + 4] = (__bf16)b[i]; }
            *(bf16x8*)(enc_b + g) = o;
        } else {
            const size_t g = (size_t)(bid - 200) * 2048 + (size_t)tid * 8;
            const unsigned row = (unsigned)(g / 640u);
            if (row < 320u) {
                floatx4 a = *(const floatx4*)(dec + g);
                floatx4 b = *(const floatx4*)(dec + g + 4);
#pragma unroll
                for (int i = 0; i < 4; i++) { o[i] = (__bf16)a[i]; o[i + 4] = (__bf16)b[i]; }
            } else {
#pragma unroll
                for (int i = 0; i < 8; i++) o[i] = (__bf16)0.0f;
            }
            *(bf16x8*)(dec_b + g) = o;
        }
        return;
    }

    // 32x32 tile transposes: src is K x N (ld = nld), dst is N x 640 bf16
    const float* src; __bf16* dst; int nld, tn, tk;
    if (bid < 720)       { int t = bid - 320;  src = W1;             dst = W1t_enc; nld = 640;  tn = t % 20; tk = t / 20; }
    else if (bid < 1120) { int t = bid - 720;  src = W1 + 640 * 640; dst = W1t_dec; nld = 640;  tn = t % 20; tk = t / 20; }
    else                 { int t = bid - 1120; src = W2;             dst = W2t;     nld = 1024; tn = t % 32; tk = t / 32; }
    const int tx = tid & 31, ty = tid >> 5;
#pragma unroll
    for (int i = 0; i < 4; i++)
        tile[ty + i * 8][tx] = (__bf16)src[(size_t)(tk * 32 + ty + i * 8) * nld + tn * 32 + tx];
    __syncthreads();
#pragma unroll
    for (int i = 0; i < 4; i++)
        dst[(size_t)(tn * 32 + ty + i * 8) * D_ + tk * 32 + tx] = tile[tx][ty + i * 8];
}

// ---------------------------------------------------------------------------
// Kernel 2: bf16 MFMA projections.  M-tiles 0..4 = enc (out encp),
// 5..7 = dec (padded to 384 rows; only rows <320 stored, out decp).
// Same verified m97 structure as the main GEMM (128x128 tile, BK=32).
// ---------------------------------------------------------------------------
__global__ __launch_bounds__(256) void proj_gemm_kernel(
    const __bf16* __restrict__ enc_b, const __bf16* __restrict__ dec_b,
    const __bf16* __restrict__ W1t_enc, const __bf16* __restrict__ W1t_dec,
    float* __restrict__ encp, float* __restrict__ decp) {
    __shared__ __bf16 As[128 * 32];
    __shared__ __bf16 Bs[128 * 32];

    const int nt = blockIdx.x;   // 0..4
    const int mt = blockIdx.y;   // 0..7
    const bool is_enc = (mt < 5);
    const __bf16* Abase = is_enc ? enc_b + (size_t)mt * 128 * D_
                                 : dec_b + (size_t)(mt - 5) * 128 * D_;
    const __bf16* Bbase = (is_enc ? W1t_enc : W1t_dec) + (size_t)nt * 128 * D_;

    const int tid = threadIdx.x;
    const int lane = tid & 63;
    const int wave = tid >> 6;
    const int wm = (wave & 1) * 64, wn = (wave >> 1) * 64;
    const int lr = lane & 15, qd = lane >> 4;

    const int r = tid >> 2;
    const int c = (tid & 3) * 8;
    const __bf16* Ag = Abase + (size_t)r * D_ + c;
    const __bf16* Bg = Bbase + (size_t)r * D_ + c;
    __bf16* Al = &As[r * 32 + c];
    __bf16* Bl = &Bs[r * 32 + c];

    floatx4 acc[4][4] = {};
    for (int k0 = 0; k0 < D_; k0 += 32) {
        __syncthreads();
        g2l16(Ag + k0,            Al);
        g2l16(Ag + k0 + 64 * D_,  Al + 64 * 32);
        g2l16(Bg + k0,            Bl);
        g2l16(Bg + k0 + 64 * D_,  Bl + 64 * 32);
        __syncthreads();

        bf16x8 af[4], wf[4];
#pragma unroll
        for (int i = 0; i < 4; i++) af[i] = *(const bf16x8*)&As[(wm + i * 16 + lr) * 32 + qd * 8];
#pragma unroll
        for (int j = 0; j < 4; j++) wf[j] = *(const bf16x8*)&Bs[(wn + j * 16 + lr) * 32 + qd * 8];
#pragma unroll
        for (int i = 0; i < 4; i++)
#pragma unroll
            for (int j = 0; j < 4; j++)   // swapped operands: lane regs span 4 consecutive cols
                acc[i][j] = __builtin_amdgcn_mfma_f32_16x16x32_bf16(wf[j], af[i], acc[i][j], 0, 0, 0);
    }

    // Swapped C/D: local row = wm+i*16+lr, cols = wn+j*16+qd*4+(0..3)
    float* Cb = is_enc ? encp + (size_t)mt * 128 * D_ : decp + (size_t)(mt - 5) * 128 * D_;
    const int rowlim = is_enc ? 128 : 320 - (mt - 5) * 128;
#pragma unroll
    for (int i = 0; i < 4; i++) {
        const int rl = wm + i * 16 + lr;
        if (rl < rowlim) {
#pragma unroll
            for (int j = 0; j < 4; j++)
                *(floatx4*)&Cb[(size_t)rl * D_ + nt * 128 + wn + j * 16 + qd * 4] = acc[i][j];
        }
    }
}

// ---------------------------------------------------------------------------
// Kernel 3: hidden[m][h] = tanh(encp[bt][h] + decp[b*80+u][h] + b1[h]) -> bf16
// ---------------------------------------------------------------------------
__global__ __launch_bounds__(256) void hidden_kernel(
    const float* __restrict__ encp, const float* __restrict__ decp,
    const float* __restrict__ b1, __bf16* __restrict__ H) {
    const unsigned g = blockIdx.x * 256u + threadIdx.x;
    const unsigned row = g / 80u;
    const unsigned hg  = g % 80u;
    const unsigned u   = row % 80u;
    const unsigned bt  = row / 80u;
    const unsigned b   = bt / 160u;

    const float* ep = encp + (size_t)bt * D_ + hg * 8;
    const float* dp = decp + (size_t)(b * 80u + u) * D_ + hg * 8;
    const float* bp = b1 + hg * 8;

    floatx4 e0 = *(const floatx4*)ep, e1 = *(const floatx4*)(ep + 4);
    floatx4 d0 = *(const floatx4*)dp, d1 = *(const floatx4*)(dp + 4);
    floatx4 c0 = *(const floatx4*)bp, c1 = *(const floatx4*)(bp + 4);

    bf16x8 hv;
#pragma unroll
    for (int i = 0; i < 4; i++) hv[i]     = (__bf16)fast_tanh(e0[i] + d0[i] + c0[i]);
#pragma unroll
    for (int i = 0; i < 4; i++) hv[i + 4] = (__bf16)fast_tanh(e1[i] + d1[i] + c1[i]);

    *(bf16x8*)(H + (size_t)g * 8) = hv;
}

// ---------------------------------------------------------------------------
// Kernel 4: C[51200x1024] = H @ W2t^T + b2, fp32 out. m97 structure,
// swapped-operand epilogue for float4 C-stores.
// ---------------------------------------------------------------------------
__global__ __launch_bounds__(256) void gemm_kernel(
    const __bf16* __restrict__ H, const __bf16* __restrict__ W2t,
    const float* __restrict__ b2, float* __restrict__ C) {
    __shared__ __bf16 As[128 * 32];
    __shared__ __bf16 Bs[128 * 32];

    const int bx = blockIdx.x;
    const int nt = bx & 7;        // XCD round-robin: W2t strip stays in each XCD's L2
    const int mt = bx >> 3;
    const int m0 = mt * 128, n0 = nt * 128;

    const int tid = threadIdx.x;
    const int lane = tid & 63;
    const int wave = tid >> 6;
    const int wm = (wave & 1) * 64, wn = (wave >> 1) * 64;
    const int lr = lane & 15, qd = lane >> 4;

    const int r = tid >> 2;
    const int c = (tid & 3) * 8;
    const __bf16* Ag = H   + (size_t)(m0 + r) * D_ + c;
    const __bf16* Bg = W2t + (size_t)(n0 + r) * D_ + c;
    __bf16* Al = &As[r * 32 + c];
    __bf16* Bl = &Bs[r * 32 + c];

    floatx4 acc[4][4] = {};

    for (int k0 = 0; k0 < D_; k0 += 32) {
        __syncthreads();
        g2l16(Ag + k0,            Al);
        g2l16(Ag + k0 + 64 * D_,  Al + 64 * 32);
        g2l16(Bg + k0,            Bl);
        g2l16(Bg + k0 + 64 * D_,  Bl + 64 * 32);
        __syncthreads();

        bf16x8 af[4], wf[4];
#pragma unroll
        for (int i = 0; i < 4; i++) af[i] = *(const bf16x8*)&As[(wm + i * 16 + lr) * 32 + qd * 8];
#pragma unroll
        for (int j = 0; j < 4; j++) wf[j] = *(const bf16x8*)&Bs[(wn + j * 16 + lr) * 32 + qd * 8];
#pragma unroll
        for (int i = 0; i < 4; i++)
#pragma unroll
            for (int j = 0; j < 4; j++)   // swapped: lane's 4 regs = 4 consecutive n
                acc[i][j] = __builtin_amdgcn_mfma_f32_16x16x32_bf16(wf[j], af[i], acc[i][j], 0, 0, 0);
    }

    // row = m0+wm+i*16+lr ; cols = n0+wn+j*16+qd*4+(0..3) -> float4 stores
#pragma unroll
    for (int j = 0; j < 4; j++) {
        const floatx4 bj = *(const floatx4*)&b2[n0 + wn + j * 16 + qd * 4];
#pragma unroll
        for (int i = 0; i < 4; i++) {
            floatx4 v = acc[i][j] + bj;
            *(floatx4*)&C[(size_t)(m0 + wm + i * 16 + lr) * V_ + n0 + wn + j * 16 + qd * 4] = v;
        }
    }
}

// ---------------------------------------------------------------------------
extern "C" void kernel_launch(void* const* d_in, const int* in_sizes, int n_in,
                              void* d_out, int out_size, void* d_ws, size_t ws_size,
                              hipStream_t stream) {
    const float* enc = (const float*)d_in[0];
    const float* dec = (const float*)d_in[1];
    const float* W1  = (const float*)d_in[2];
    const float* b1  = (const float*)d_in[3];
    const float* W2  = (const float*)d_in[4];
    const float* b2  = (const float*)d_in[5];
    float* out = (float*)d_out;

    // Workspace (69,304,320 B total — same as round 1):
    //   encp @0 (1.64MB) | decp @1.64MB (0.82MB) | W2t @2.46MB (1.31MB)
    //   Hbuf @3.77MB (65.5MB) — its first 2.95MB is aliased by the bf16
    //   staging buffers (enc_b/dec_b/W1t_*), which are dead before
    //   hidden_kernel writes Hbuf.
    char* ws = (char*)d_ws;
    float*  encp    = (float*)ws;
    float*  decp    = (float*)(ws + 1638400);
    __bf16* W2t     = (__bf16*)(ws + 2457600);
    __bf16* Hbuf    = (__bf16*)(ws + 3768320);
    __bf16* enc_b   = (__bf16*)(ws + 3768320);            // alias (dead by k3)
    __bf16* dec_b   = (__bf16*)(ws + 4587520);
    __bf16* W1t_enc = (__bf16*)(ws + 5079040);
    __bf16* W1t_dec = (__bf16*)(ws + 5898240);

    convert_kernel<<<1760, 256, 0, stream>>>(enc, dec, W1, W2,
                                             enc_b, dec_b, W1t_enc, W1t_dec, W2t);
    proj_gemm_kernel<<<dim3(5, 8), 256, 0, stream>>>(enc_b, dec_b, W1t_enc, W1t_dec,
                                                     encp, decp);
    hidden_kernel<<<16000, 256, 0, stream>>>(encp, decp, b1, Hbuf);
    gemm_kernel<<<3200, 256, 0, stream>>>(Hbuf, W2t, b2, out);
}